// Round 2
// baseline (343.894 us; speedup 1.0000x reference)
//
#include <hip/hip_runtime.h>

#define D 32
#define EPS 1e-5f
#define TPB 256

// ---------------- S1: histogram of etype (counting sort, pass 1) ----------
__global__ void hist_kernel(const int* __restrict__ etype, int E, int R,
                            int* __restrict__ hist)
{
    __shared__ int lh[1024];
    for (int i = threadIdx.x; i < R; i += TPB) lh[i] = 0;
    __syncthreads();
    for (int e = blockIdx.x * TPB + threadIdx.x; e < E; e += gridDim.x * TPB)
        atomicAdd(&lh[etype[e]], 1);
    __syncthreads();
    for (int i = threadIdx.x; i < R; i += TPB)
        if (lh[i]) atomicAdd(&hist[i], lh[i]);
}

// ---------------- S2: exclusive scan over R bins + per-block task list ----
__global__ void scan_kernel(const int* __restrict__ hist, int R,
                            int* __restrict__ rel_start, int* __restrict__ offs,
                            int* __restrict__ task_rel, int* __restrict__ task_start,
                            int* __restrict__ n_tasks)
{
    __shared__ int s_start[1025];
    __shared__ int s_tbase[1024];
    if (threadIdx.x == 0) {
        int acc = 0, tb = 0;
        for (int r = 0; r < R; ++r) {
            s_start[r] = acc; s_tbase[r] = tb;
            int n = hist[r];
            acc += n; tb += (n + TPB - 1) / TPB;
        }
        s_start[R] = acc;
        rel_start[R] = acc;
        *n_tasks = tb;
    }
    __syncthreads();
    for (int r = threadIdx.x; r < R; r += TPB) {
        int st = s_start[r];
        rel_start[r] = st;
        offs[r] = st;                      // working cursor for sort pass
        int n  = s_start[r + 1] - st;
        int nb = (n + TPB - 1) / TPB;
        int tb = s_tbase[r];
        for (int b = 0; b < nb; ++b) {
            task_rel[tb + b]   = r;
            task_start[tb + b] = st + b * TPB;
        }
    }
}

// ---------------- S3: scatter src/dst into etype-sorted order -------------
__global__ void sort_kernel(const int* __restrict__ src, const int* __restrict__ dst,
                            const int* __restrict__ etype, int E,
                            int* __restrict__ offs,
                            int* __restrict__ ssrc, int* __restrict__ sdst)
{
    for (int e = blockIdx.x * TPB + threadIdx.x; e < E; e += gridDim.x * TPB) {
        int p = atomicAdd(&offs[etype[e]], 1);
        ssrc[p] = src[e];
        sdst[p] = dst[e];
    }
}

// ---------------- P2: main fused pass -------------------------------------
// One block = up to 256 edges of ONE relation (task list guarantees this).
// Per thread: one edge, all 32 outputs in registers; W via SGPR s_loads
// (r is wave-uniform). h rows staged coalesced into pad-33 LDS. Raw relu
// messages scatter-added (coalesced via LDS transpose) into out; BN batch
// stats (sum, sumsq) block-reduced then atomically accumulated.
__global__ __launch_bounds__(TPB)
void rgcn_main(const float* __restrict__ h, const float* __restrict__ W,
               const int* __restrict__ rel_start,
               const int* __restrict__ task_rel, const int* __restrict__ task_start,
               const int* __restrict__ n_tasks_p,
               const int* __restrict__ ssrc, const int* __restrict__ sdst,
               float* __restrict__ out,
               float* __restrict__ stat_sum, float* __restrict__ stat_sq,
               float* __restrict__ cnt)
{
    __shared__ float s_tile[TPB * 33];    // h rows, then reused for msg rows
    __shared__ int   s_src[TPB];
    __shared__ int   s_dst[TPB];
    __shared__ float s_aux[2 * TPB];

    const int task = blockIdx.x;
    if (task >= *n_tasks_p) return;
    const int r      = task_rel[task];
    const int start  = task_start[task];
    const int relEnd = rel_start[r + 1];
    const int nE     = min(TPB, relEnd - start);
    const int tid    = threadIdx.x;

    if (tid < nE) {
        s_src[tid] = ssrc[start + tid];
        s_dst[tid] = sdst[start + tid];
    }
    __syncthreads();

    // stage h rows: 8 lanes per row, float4 each -> fully coalesced global
    for (int i = tid; i < nE * 8; i += TPB) {
        const int row = i >> 3, seg = i & 7;
        const float4 v = *(const float4*)(h + (size_t)s_src[row] * D + seg * 4);
        float* p = &s_tile[row * 33 + seg * 4];
        p[0] = v.x; p[1] = v.y; p[2] = v.z; p[3] = v.w;
    }
    __syncthreads();

    // wave-uniform relation matrix -> SGPR path
    const float* Wr = W + (size_t)__builtin_amdgcn_readfirstlane(r) * (D * D);

    float acc[D];
#pragma unroll
    for (int o = 0; o < D; ++o) acc[o] = 0.f;

    if (tid < nE) {
#pragma unroll 4
        for (int d = 0; d < D; ++d) {
            const float hd = s_tile[tid * 33 + d];
#pragma unroll
            for (int o = 0; o < D; ++o)
                acc[o] = fmaf(hd, Wr[d * D + o], acc[o]);
        }
#pragma unroll
        for (int o = 0; o < D; ++o) acc[o] = fmaxf(acc[o], 0.f);
        atomicAdd(&cnt[s_dst[tid]], 1.0f);
    }
    __syncthreads();   // done reading h tile

    if (tid < nE) {
#pragma unroll
        for (int o = 0; o < D; ++o) s_tile[tid * 33 + o] = acc[o];
    }
    __syncthreads();

    // transpose-scatter (coalesced 128B atomics per 32-lane group) + stats
    float ps = 0.f, pq = 0.f;
    for (int i = tid; i < nE * D; i += TPB) {
        const int row = i >> 5, o = i & 31;      // o == tid&31, constant
        const float v = s_tile[row * 33 + o];
        atomicAdd(&out[(size_t)s_dst[row] * D + o], v);
        ps += v; pq += v * v;
    }
    s_aux[tid]       = ps;
    s_aux[TPB + tid] = pq;
    __syncthreads();
    if (tid < D) {
        float ss = 0.f, sq = 0.f;
#pragma unroll
        for (int c = 0; c < TPB / D; ++c) {
            ss += s_aux[c * D + tid];
            sq += s_aux[TPB + c * D + tid];
        }
        atomicAdd(&stat_sum[tid], ss);
        atomicAdd(&stat_sq[tid], sq);
    }
}

// ---------------- finalize: BN affine folded into segment-mean ------------
// node mean of normalized msgs = (sc*rawsum + sh*cnt) / max(cnt,1)
__global__ void finalize_kernel(float* __restrict__ out, const float* __restrict__ cnt,
                                const float* __restrict__ stat_sum,
                                const float* __restrict__ stat_sq,
                                const float* __restrict__ gamma,
                                const float* __restrict__ beta,
                                float invE, int total)
{
    const int i = blockIdx.x * TPB + threadIdx.x;
    if (i >= total) return;
    const int o    = i & 31;
    const int node = i >> 5;
    const float mu  = stat_sum[o] * invE;
    const float var = fmaxf(stat_sq[o] * invE - mu * mu, 0.f);
    const float is  = rsqrtf(var + EPS);
    const float sc  = gamma[o] * is;
    const float sh  = fmaf(-mu, sc, beta[o]);
    const float c   = cnt[node];
    out[i] = fmaf(out[i], sc, sh * c) / fmaxf(c, 1.0f);
}

extern "C" void kernel_launch(void* const* d_in, const int* in_sizes, int n_in,
                              void* d_out, int out_size, void* d_ws, size_t ws_size,
                              hipStream_t stream)
{
    const float* h     = (const float*)d_in[0];   // [N, D]
    const float* W     = (const float*)d_in[1];   // [R, D, D]
    const float* gamma = (const float*)d_in[2];   // [D]
    const float* beta  = (const float*)d_in[3];   // [D]
    const int*   src   = (const int*)d_in[4];     // [E]
    const int*   dst   = (const int*)d_in[5];     // [E]
    const int*   etype = (const int*)d_in[6];     // [E]
    float* out = (float*)d_out;                   // [N, D]

    const int E = in_sizes[4];
    const int N = in_sizes[0] / D;
    const int R = in_sizes[1] / (D * D);
    const int T = R + (E + TPB - 1) / TPB;        // max task count

    // ws layout: [zeroed: hist R | stat_sum 32 | stat_sq 32 | cnt N]
    //            [rel_start R+1 | offs R | n_tasks 1 | task_rel T | task_start T |
    //             ssrc E | sdst E]
    int*   hist      = (int*)d_ws;
    float* stat_sum  = (float*)(hist + R);
    float* stat_sq   = stat_sum + D;
    float* cnt       = stat_sq + D;
    int*   rel_start = (int*)(cnt + N);
    int*   offs      = rel_start + R + 1;
    int*   n_tasks   = offs + R;
    int*   task_rel  = n_tasks + 1;
    int*   task_start= task_rel + T;
    int*   ssrc      = task_start + T;
    int*   sdst      = ssrc + E;

    hipMemsetAsync(d_ws, 0, sizeof(int) * (size_t)(R + 2 * D + N), stream);
    hipMemsetAsync(d_out, 0, sizeof(float) * (size_t)out_size, stream);

    hist_kernel<<<256, TPB, 0, stream>>>(etype, E, R, hist);
    scan_kernel<<<1, TPB, 0, stream>>>(hist, R, rel_start, offs,
                                       task_rel, task_start, n_tasks);
    sort_kernel<<<256, TPB, 0, stream>>>(src, dst, etype, E, offs, ssrc, sdst);
    rgcn_main<<<T, TPB, 0, stream>>>(h, W, rel_start, task_rel, task_start,
                                     n_tasks, ssrc, sdst, out,
                                     stat_sum, stat_sq, cnt);
    finalize_kernel<<<(N * D + TPB - 1) / TPB, TPB, 0, stream>>>(
        out, cnt, stat_sum, stat_sq, gamma, beta, 1.0f / (float)E, N * D);
}

// Round 3
// 153.096 us; speedup vs baseline: 2.2463x; 2.2463x over previous
//
#include <hip/hip_runtime.h>

#define D 32
#define EPS 1e-5f
#define TPB 256
#define NB 256          // blocks for the counting-sort passes (fixed chunking)

// ---------------- S1: per-block histogram (transposed store) --------------
__global__ void hist2_kernel(const int* __restrict__ etype, int E, int R, int chunk,
                             int* __restrict__ blockHistT)   // [R][NB]
{
    __shared__ int lh[1024];
    for (int i = threadIdx.x; i < R; i += TPB) lh[i] = 0;
    __syncthreads();
    const int lo = blockIdx.x * chunk, hi = min(E, lo + chunk);
    for (int e = lo + threadIdx.x; e < hi; e += TPB)
        atomicAdd(&lh[etype[e]], 1);
    __syncthreads();
    for (int r = threadIdx.x; r < R; r += TPB)
        blockHistT[r * NB + blockIdx.x] = lh[r];
}

// ---------------- S2: per-relation scan across blocks + task list ---------
// blockHistT becomes, in place, the exclusive prefix (per relation, over
// blocks): each sort block's private base within its relation's segment.
__global__ void scan2_kernel(int* __restrict__ blockHistT, int R,
                             int* __restrict__ rel_start,
                             int* __restrict__ task_rel, int* __restrict__ task_start,
                             int* __restrict__ n_tasks)
{
    __shared__ int tot[1024];
    __shared__ int s_start[1025];
    __shared__ int s_tbase[1024];
    const int r = threadIdx.x;
    if (r < R) {
        int acc = 0;
        int* p = blockHistT + r * NB;
        for (int b = 0; b < NB; ++b) { int v = p[b]; p[b] = acc; acc += v; }
        tot[r] = acc;
    }
    __syncthreads();
    if (threadIdx.x == 0) {
        int acc = 0, tb = 0;
        for (int rr = 0; rr < R; ++rr) {
            s_start[rr] = acc; s_tbase[rr] = tb;
            acc += tot[rr];
            tb  += (tot[rr] + TPB - 1) / TPB;
        }
        s_start[R] = acc;
        rel_start[R] = acc;
        *n_tasks = tb;
    }
    __syncthreads();
    if (r < R) {
        const int st = s_start[r];
        rel_start[r] = st;
        const int nb = (tot[r] + TPB - 1) / TPB;
        const int tb = s_tbase[r];
        for (int b = 0; b < nb; ++b) {
            task_rel[tb + b]   = r;
            task_start[tb + b] = st + b * TPB;
        }
    }
}

// ---------------- S3: scatter into sorted order (no global atomics) -------
__global__ void scatter2_kernel(const int* __restrict__ src, const int* __restrict__ dst,
                                const int* __restrict__ etype, int E, int R, int chunk,
                                const int* __restrict__ blockHistT,
                                const int* __restrict__ rel_start,
                                int* __restrict__ ssrc, int* __restrict__ sdst)
{
    __shared__ int cur[1024];
    for (int r = threadIdx.x; r < R; r += TPB)
        cur[r] = rel_start[r] + blockHistT[r * NB + blockIdx.x];
    __syncthreads();
    const int lo = blockIdx.x * chunk, hi = min(E, lo + chunk);
    for (int e = lo + threadIdx.x; e < hi; e += TPB) {
        const int p = atomicAdd(&cur[etype[e]], 1);   // LDS atomic only
        ssrc[p] = src[e];
        sdst[p] = dst[e];
    }
}

// ---------------- P2: main fused pass (unchanged from R2) -----------------
__global__ __launch_bounds__(TPB)
void rgcn_main(const float* __restrict__ h, const float* __restrict__ W,
               const int* __restrict__ rel_start,
               const int* __restrict__ task_rel, const int* __restrict__ task_start,
               const int* __restrict__ n_tasks_p,
               const int* __restrict__ ssrc, const int* __restrict__ sdst,
               float* __restrict__ out,
               float* __restrict__ stat_sum, float* __restrict__ stat_sq,
               float* __restrict__ cnt)
{
    __shared__ float s_tile[TPB * 33];
    __shared__ int   s_src[TPB];
    __shared__ int   s_dst[TPB];
    __shared__ float s_aux[2 * TPB];

    const int task = blockIdx.x;
    if (task >= *n_tasks_p) return;
    const int r      = task_rel[task];
    const int start  = task_start[task];
    const int relEnd = rel_start[r + 1];
    const int nE     = min(TPB, relEnd - start);
    const int tid    = threadIdx.x;

    if (tid < nE) {
        s_src[tid] = ssrc[start + tid];
        s_dst[tid] = sdst[start + tid];
    }
    __syncthreads();

    for (int i = tid; i < nE * 8; i += TPB) {
        const int row = i >> 3, seg = i & 7;
        const float4 v = *(const float4*)(h + (size_t)s_src[row] * D + seg * 4);
        float* p = &s_tile[row * 33 + seg * 4];
        p[0] = v.x; p[1] = v.y; p[2] = v.z; p[3] = v.w;
    }
    __syncthreads();

    const float* Wr = W + (size_t)__builtin_amdgcn_readfirstlane(r) * (D * D);

    float acc[D];
#pragma unroll
    for (int o = 0; o < D; ++o) acc[o] = 0.f;

    if (tid < nE) {
#pragma unroll 4
        for (int d = 0; d < D; ++d) {
            const float hd = s_tile[tid * 33 + d];
#pragma unroll
            for (int o = 0; o < D; ++o)
                acc[o] = fmaf(hd, Wr[d * D + o], acc[o]);
        }
#pragma unroll
        for (int o = 0; o < D; ++o) acc[o] = fmaxf(acc[o], 0.f);
        atomicAdd(&cnt[s_dst[tid]], 1.0f);
    }
    __syncthreads();

    if (tid < nE) {
#pragma unroll
        for (int o = 0; o < D; ++o) s_tile[tid * 33 + o] = acc[o];
    }
    __syncthreads();

    float ps = 0.f, pq = 0.f;
    for (int i = tid; i < nE * D; i += TPB) {
        const int row = i >> 5, o = i & 31;
        const float v = s_tile[row * 33 + o];
        atomicAdd(&out[(size_t)s_dst[row] * D + o], v);
        ps += v; pq += v * v;
    }
    s_aux[tid]       = ps;
    s_aux[TPB + tid] = pq;
    __syncthreads();
    if (tid < D) {
        float ss = 0.f, sq = 0.f;
#pragma unroll
        for (int c = 0; c < TPB / D; ++c) {
            ss += s_aux[c * D + tid];
            sq += s_aux[TPB + c * D + tid];
        }
        atomicAdd(&stat_sum[tid], ss);
        atomicAdd(&stat_sq[tid], sq);
    }
}

// ---------------- finalize: BN affine folded into segment-mean ------------
__global__ void finalize_kernel(float* __restrict__ out, const float* __restrict__ cnt,
                                const float* __restrict__ stat_sum,
                                const float* __restrict__ stat_sq,
                                const float* __restrict__ gamma,
                                const float* __restrict__ beta,
                                float invE, int total)
{
    const int i = blockIdx.x * TPB + threadIdx.x;
    if (i >= total) return;
    const int o    = i & 31;
    const int node = i >> 5;
    const float mu  = stat_sum[o] * invE;
    const float var = fmaxf(stat_sq[o] * invE - mu * mu, 0.f);
    const float is  = rsqrtf(var + EPS);
    const float sc  = gamma[o] * is;
    const float sh  = fmaf(-mu, sc, beta[o]);
    const float c   = cnt[node];
    out[i] = fmaf(out[i], sc, sh * c) / fmaxf(c, 1.0f);
}

extern "C" void kernel_launch(void* const* d_in, const int* in_sizes, int n_in,
                              void* d_out, int out_size, void* d_ws, size_t ws_size,
                              hipStream_t stream)
{
    const float* h     = (const float*)d_in[0];
    const float* W     = (const float*)d_in[1];
    const float* gamma = (const float*)d_in[2];
    const float* beta  = (const float*)d_in[3];
    const int*   src   = (const int*)d_in[4];
    const int*   dst   = (const int*)d_in[5];
    const int*   etype = (const int*)d_in[6];
    float* out = (float*)d_out;

    const int E = in_sizes[4];
    const int N = in_sizes[0] / D;
    const int R = in_sizes[1] / (D * D);
    const int T = R + (E + TPB - 1) / TPB;        // max task count
    const int chunk = (E + NB - 1) / NB;

    // ws layout (ints/floats, 4B each):
    // [zeroed: stat_sum 32 | stat_sq 32 | cnt N]
    // [rel_start R+1 | n_tasks 1 | task_rel T | task_start T |
    //  blockHistT R*NB | ssrc E | sdst E]
    float* stat_sum  = (float*)d_ws;
    float* stat_sq   = stat_sum + D;
    float* cnt       = stat_sq + D;
    int*   rel_start = (int*)(cnt + N);
    int*   n_tasks   = rel_start + R + 1;
    int*   task_rel  = n_tasks + 1;
    int*   task_start= task_rel + T;
    int*   blockHistT= task_start + T;
    int*   ssrc      = blockHistT + R * NB;
    int*   sdst      = ssrc + E;

    hipMemsetAsync(d_ws, 0, sizeof(float) * (size_t)(2 * D + N), stream);
    hipMemsetAsync(d_out, 0, sizeof(float) * (size_t)out_size, stream);

    hist2_kernel<<<NB, TPB, 0, stream>>>(etype, E, R, chunk, blockHistT);
    scan2_kernel<<<1, TPB, 0, stream>>>(blockHistT, R, rel_start,
                                        task_rel, task_start, n_tasks);
    scatter2_kernel<<<NB, TPB, 0, stream>>>(src, dst, etype, E, R, chunk,
                                            blockHistT, rel_start, ssrc, sdst);
    rgcn_main<<<T, TPB, 0, stream>>>(h, W, rel_start, task_rel, task_start,
                                     n_tasks, ssrc, sdst, out,
                                     stat_sum, stat_sq, cnt);
    finalize_kernel<<<(N * D + TPB - 1) / TPB, TPB, 0, stream>>>(
        out, cnt, stat_sum, stat_sq, gamma, beta, 1.0f / (float)E, N * D);
}